// Round 7
// baseline (32.168 us; speedup 1.0000x reference)
//
#include <hip/hip_runtime.h>

// DiffNet, single dispatch, 3 phases, fence-free SELF-CLEANING grid barrier.
// Math (exact collapse of the two 1x1 convs -- affine in meta):
//   Wv = vi @ W.T (pre-bias), vj = relu(Wv + b)
//   A_c = sum_h c2w[h]*c1w[h][c],  D = sum_h c2w[h]*c1b[h] + c2b
//   s1 = sum_i vi, s2 = sum_i vi^2 (per row)
//   delta = scale*(A0*s2 + A1*Wv + (A2*vj + D)*s1),  out = vj + delta
//
// Inter-phase tensors t1/t2 exchanged via relaxed AGENT-scope 64-bit atomics
// (coherent at L3, no cache fences anywhere). Barrier counters are MONOTONIC
// epoch counters in zero-initialized __device__ globals: no per-launch reset,
// no hipMemsetAsync node. Each launch: every grp counter +16, gc +64, flag +2
// -- all invariants (mod 8 / mod 32 / epoch base) preserved across launches,
// so every call performs identical work (deterministic output).

#define NBLK 256

__device__ unsigned int g_grp[32 * 32];   // 32 group counters, 128B apart
__device__ unsigned int g_gc;             // global closer counter
__device__ unsigned int g_flag;           // epoch flag (monotonic)

__device__ __forceinline__ void gridbar(int bid, unsigned int target) {
    __syncthreads();
    if (threadIdx.x == 0) {
        // t1/t2 data stores are relaxed atomics issued by this wave; vmcnt(0)
        // guarantees they reached the coherent point before we announce arrival.
        asm volatile("s_waitcnt vmcnt(0)" ::: "memory");
        const int g = bid >> 3;   // 32 groups of 8 blocks
        unsigned p = __hip_atomic_fetch_add(&g_grp[g * 32], 1u,
                          __ATOMIC_RELAXED, __HIP_MEMORY_SCOPE_AGENT);
        if ((p & 7u) == 7u) {
            unsigned q = __hip_atomic_fetch_add(&g_gc, 1u,
                              __ATOMIC_RELAXED, __HIP_MEMORY_SCOPE_AGENT);
            if ((q & 31u) == 31u)
                __hip_atomic_store(&g_flag, target,          // single writer
                                   __ATOMIC_RELAXED, __HIP_MEMORY_SCOPE_AGENT);
        }
        while ((int)(__hip_atomic_load(&g_flag, __ATOMIC_RELAXED,
                                       __HIP_MEMORY_SCOPE_AGENT) - target) < 0)
            __builtin_amdgcn_s_sleep(1);   // ~64cy backoff: keep flag bank breathable
        asm volatile("" ::: "memory");
    }
    __syncthreads();
}

#define KEEP4(v) asm volatile("" :: "v"((v).x), "v"((v).y), "v"((v).z), "v"((v).w))
#define KEEP1(v) asm volatile("" :: "v"(v))

// AIN:  stage input via relaxed agent atomic u64 loads (coherent, L2-bypass)
// AOUT: write output via relaxed agent atomic u64 stores (pairs via LDS regroup)
template<int IIN, int OUT, int ROWS, bool AIN, bool AOUT>
__device__ __forceinline__ void phase(const float* __restrict__ vin,   // [32, IIN]
                                      const float4* __restrict__ wreg, // IIN/256 regs
                                      float biasc,                     // bias[col]
                                      float* __restrict__ vout,        // [32, OUT]
                                      float* __restrict__ lds,
                                      float* __restrict__ s1s,
                                      float* __restrict__ s2s,
                                      float* __restrict__ svals,       // [4*16]
                                      int bid, int lane, int wave,
                                      float A0, float A1, float A2,
                                      float Dd, float scale)
{
    constexpr int CBLK = OUT / 4;          // 4 cols/block, 1 per wave
    const int row0 = (bid / CBLK) * ROWS;
    const int col  = (bid % CBLK) * 4 + wave;

    // ---- stage ROWS x IIN rows into LDS ----
    if (AIN) {
        const unsigned long long* src = reinterpret_cast<const unsigned long long*>(
            vin + (size_t)row0 * IIN);
        float2* dst = reinterpret_cast<float2*>(lds);
        constexpr int N2 = ROWS * IIN / 2;
        #pragma unroll
        for (int k = 0; k < N2 / 256; ++k) {
            unsigned long long u = __hip_atomic_load(
                &src[k * 256 + threadIdx.x], __ATOMIC_RELAXED, __HIP_MEMORY_SCOPE_AGENT);
            float2 f;
            __builtin_memcpy(&f, &u, 8);
            dst[k * 256 + threadIdx.x] = f;
        }
    } else {
        const float4* src = reinterpret_cast<const float4*>(vin + (size_t)row0 * IIN);
        float4* dst = reinterpret_cast<float4*>(lds);
        constexpr int N4 = ROWS * IIN / 4;
        #pragma unroll
        for (int k = 0; k < N4 / 256; ++k)
            dst[k * 256 + threadIdx.x] = src[k * 256 + threadIdx.x];
    }
    __syncthreads();

    // ---- per-row s1, s2 (wave-parallel) ----
    constexpr int RPW = ROWS / 4;
    #pragma unroll
    for (int r = 0; r < RPW; ++r) {
        const int b = wave * RPW + r;
        const float4* v4 = reinterpret_cast<const float4*>(lds + b * IIN);
        float p1 = 0.f, p2 = 0.f;
        #pragma unroll
        for (int q = 0; q < IIN / 256; ++q) {
            const float4 a = v4[q * 64 + lane];
            p1 += (a.x + a.y) + (a.z + a.w);
            p2 += a.x * a.x + a.y * a.y + a.z * a.z + a.w * a.w;
        }
        #pragma unroll
        for (int s = 32; s > 0; s >>= 1) {
            p1 += __shfl_xor(p1, s);
            p2 += __shfl_xor(p2, s);
        }
        if (lane == 0) { s1s[b] = p1; s2s[b] = p2; }
    }

    // ---- dot products: wave's column (prefetched W) vs ROWS staged rows ----
    float acc[ROWS];
    #pragma unroll
    for (int r = 0; r < ROWS; ++r) acc[r] = 0.f;

    #pragma unroll
    for (int q = 0; q < IIN / 256; ++q) {
        const float4 w4 = wreg[q];
        #pragma unroll
        for (int r = 0; r < ROWS; ++r) {
            const float4 v4 = *reinterpret_cast<const float4*>(
                lds + r * IIN + (q * 64 + lane) * 4);
            acc[r] = fmaf(w4.w, v4.w, fmaf(w4.z, v4.z,
                     fmaf(w4.y, v4.y, fmaf(w4.x, v4.x, acc[r]))));
        }
    }

    // ---- reduce; lane r keeps row r's total ----
    float Wv = 0.f;
    #pragma unroll
    for (int r = 0; r < ROWS; ++r) {
        float t = acc[r];
        #pragma unroll
        for (int s = 32; s > 0; s >>= 1) t += __shfl_xor(t, s);
        if (lane == r) Wv = t;
    }

    __syncthreads();   // s1s/s2s complete before epilogue reads

    // ---- epilogue ----
    float val = 0.f;
    if (lane < ROWS) {
        const float vj = fmaxf(Wv + biasc, 0.f);
        val = vj + scale * (A0 * s2s[lane] + A1 * Wv + (A2 * vj + Dd) * s1s[lane]);
    }

    if (AOUT) {
        if (lane < ROWS) svals[wave * 16 + lane] = val;
        __syncthreads();
        // pack col pairs (w,w+1), w in {0,2}; 8-byte aligned since colbase%4==0
        if (threadIdx.x < 2 * ROWS) {
            const int w2 = (threadIdx.x >= ROWS) ? 2 : 0;
            const int r  = threadIdx.x & (ROWS - 1);
            float2 f = make_float2(svals[w2 * 16 + r], svals[(w2 + 1) * 16 + r]);
            unsigned long long u;
            __builtin_memcpy(&u, &f, 8);
            unsigned long long* dst = reinterpret_cast<unsigned long long*>(
                vout + (size_t)(row0 + r) * OUT + (bid % CBLK) * 4 + w2);
            __hip_atomic_store(dst, u, __ATOMIC_RELAXED, __HIP_MEMORY_SCOPE_AGENT);
        }
    } else {
        if (lane < ROWS)
            vout[(size_t)(row0 + lane) * OUT + col] = val;   // final output: plain
    }
}

__global__ void __launch_bounds__(256, 1)
diffnet_onekernel(const float* __restrict__ x,
                  const float* __restrict__ W1, const float* __restrict__ b1,
                  const float* __restrict__ W2, const float* __restrict__ b2,
                  const float* __restrict__ W3, const float* __restrict__ b3,
                  const float* __restrict__ c1w, const float* __restrict__ c1b,
                  const float* __restrict__ c2w, const float* __restrict__ c2b,
                  const int* __restrict__ bn,
                  float* __restrict__ t1, float* __restrict__ t2,
                  float* __restrict__ out)
{
    __shared__ float lds[16 * 1024];
    __shared__ float s1s[16], s2s[16];
    __shared__ float svals[4 * 16];

    const int bid  = blockIdx.x;
    const int lane = threadIdx.x & 63;
    const int wave = threadIdx.x >> 6;

    // epoch base: read BEFORE arriving at any barrier (race-free: the flag
    // cannot advance until this block itself arrives at barrier 1)
    unsigned F0 = 0;
    if (threadIdx.x == 0)
        F0 = __hip_atomic_load(&g_flag, __ATOMIC_RELAXED, __HIP_MEMORY_SCOPE_AGENT);

    // collapsed conv constants (uniform scalar loads)
    float A0 = 0.f, A1 = 0.f, A2 = 0.f, Dd = c2b[0];
    #pragma unroll
    for (int h = 0; h < 8; ++h) {
        const float w2 = c2w[h];
        A0 = fmaf(w2, c1w[h * 3 + 0], A0);
        A1 = fmaf(w2, c1w[h * 3 + 1], A1);
        A2 = fmaf(w2, c1w[h * 3 + 2], A2);
        Dd = fmaf(w2, c1b[h], Dd);
    }
    const int raw = bn[0];
    const float bnf = (raw > 0 && raw < 1000000) ? (float)raw : __int_as_float(raw);
    const float scale = 0.1f / bnf;

    const int col12 = (bid & 127) * 4 + wave;   // phase 1/2 column
    const int col3  = (bid & 63) * 4 + wave;    // phase 3 column

    // ---- prefetch phase-1 weights (overlaps x staging) ----
    float4 w1r[4];
    {
        const float4* Wr = reinterpret_cast<const float4*>(W1 + (size_t)col12 * 1024);
        #pragma unroll
        for (int q = 0; q < 4; ++q) w1r[q] = Wr[q * 64 + lane];
    }
    const float bias1 = b1[col12];

    // phase 1: x[32,1024] -> t1[32,512]   (128 colblk x 2 rowblk, atomic out)
    phase<1024, 512, 16, false, true>(x, w1r, bias1, t1, lds, s1s, s2s, svals,
                                      bid, lane, wave, A0, A1, A2, Dd, scale);

    // ---- prefetch phase-2 weights BEFORE the barrier ----
    float4 w2r[2];
    {
        const float4* Wr = reinterpret_cast<const float4*>(W2 + (size_t)col12 * 512);
        #pragma unroll
        for (int q = 0; q < 2; ++q) w2r[q] = Wr[q * 64 + lane];
    }
    const float bias2 = b2[col12];
    KEEP4(w2r[0]); KEEP4(w2r[1]); KEEP1(bias2);

    gridbar(bid, F0 + 1);

    // phase 2: t1 -> t2[32,512]   (atomic in, atomic out)
    phase<512, 512, 16, true, true>(t1, w2r, bias2, t2, lds, s1s, s2s, svals,
                                    bid, lane, wave, A0, A1, A2, Dd, scale);

    // ---- prefetch phase-3 weights BEFORE the barrier ----
    float4 w3r[2];
    {
        const float4* Wr = reinterpret_cast<const float4*>(W3 + (size_t)col3 * 512);
        #pragma unroll
        for (int q = 0; q < 2; ++q) w3r[q] = Wr[q * 64 + lane];
    }
    const float bias3 = b3[col3];
    KEEP4(w3r[0]); KEEP4(w3r[1]); KEEP1(bias3);

    gridbar(bid, F0 + 2);

    // phase 3: t2 -> out[32,256]   (64 colblk x 4 rowblk, ROWS=8; atomic in, plain out)
    phase<512, 256, 8, true, false>(t2, w3r, bias3, out, lds, s1s, s2s, svals,
                                    bid, lane, wave, A0, A1, A2, Dd, scale);
}

extern "C" void kernel_launch(void* const* d_in, const int* in_sizes, int n_in,
                              void* d_out, int out_size, void* d_ws, size_t ws_size,
                              hipStream_t stream) {
    const float* x     = (const float*)d_in[0];
    const float* fc1_w = (const float*)d_in[1];
    const float* fc1_b = (const float*)d_in[2];
    const float* fc2_w = (const float*)d_in[3];
    const float* fc2_b = (const float*)d_in[4];
    const float* fc3_w = (const float*)d_in[5];
    const float* fc3_b = (const float*)d_in[6];
    const float* c1w   = (const float*)d_in[7];
    const float* c1b   = (const float*)d_in[8];
    const float* c2w   = (const float*)d_in[9];
    const float* c2b   = (const float*)d_in[10];
    const int*   bn    = (const int*)d_in[11];

    float* t1  = (float*)d_ws;                         // [32, 512] = 64KB
    float* t2  = t1 + 32 * 512;                        // [32, 512] = 64KB
    float* out = (float*)d_out;                        // [32, 256]

    diffnet_onekernel<<<dim3(NBLK), dim3(256), 0, stream>>>(
        x, fc1_w, fc1_b, fc2_w, fc2_b, fc3_w, fc3_b,
        c1w, c1b, c2w, c2b, bn, t1, t2, out);
}

// Round 8
// 21.347 us; speedup vs baseline: 1.5069x; 1.5069x over previous
//
#include <hip/hip_runtime.h>

// DiffNet, single dispatch, 3 phases, 4 INDEPENDENT 64-block barrier domains.
// Math (exact collapse of the two 1x1 convs -- affine in meta):
//   Wv = vi @ W.T (pre-bias), vj = relu(Wv + b)
//   A_c = sum_h c2w[h]*c1w[h][c],  D = sum_h c2w[h]*c1b[h] + c2b
//   s1 = sum_i vi, s2 = sum_i vi^2 (per row)
//   delta = scale*(A0*s2 + A1*Wv + (A2*vj + D)*s1),  out = vj + delta
//
// Decomposition: domain d (64 blocks) owns batch rows [d*8, d*8+8) through ALL
// layers; inter-layer dependencies are row-local, so domains never sync with
// each other. Inter-phase t1/t2 exchanged via relaxed AGENT-scope atomics
// (coherent at L3, no cache fences). Barrier: single monotonic counter per
// domain; last arriver stores the epoch flag (2-level chain). Counters live in
// zero-initialized __device__ globals and are never reset (all invariants
// mod-64 / epoch-base preserved across launches -> deterministic replays).

#define DOMS 4
#define BPD  64                    // blocks per domain
#define NBLK (DOMS * BPD)

__device__ unsigned int g_cnt[DOMS * 32];    // arrival counters, 128B apart
__device__ unsigned int g_flag[DOMS * 32];   // epoch flags, 128B apart

__device__ __forceinline__ void gridbar(int dom, unsigned int target) {
    __syncthreads();
    if (threadIdx.x == 0) {
        // data stores (relaxed L3 atomics) issued by this wave are covered by
        // vmcnt; other waves drained at the __syncthreads above.
        asm volatile("s_waitcnt vmcnt(0)" ::: "memory");
        unsigned int old = __hip_atomic_fetch_add(&g_cnt[dom * 32], 1u,
                               __ATOMIC_RELAXED, __HIP_MEMORY_SCOPE_AGENT);
        if ((old & (BPD - 1u)) == (BPD - 1u))
            __hip_atomic_store(&g_flag[dom * 32], target,     // single writer
                               __ATOMIC_RELAXED, __HIP_MEMORY_SCOPE_AGENT);
        while ((int)(__hip_atomic_load(&g_flag[dom * 32], __ATOMIC_RELAXED,
                                       __HIP_MEMORY_SCOPE_AGENT) - target) < 0)
            __builtin_amdgcn_s_sleep(1);
        asm volatile("" ::: "memory");
    }
    __syncthreads();
}

#define KEEP4(v) asm volatile("" :: "v"((v).x), "v"((v).y), "v"((v).z), "v"((v).w))
#define KEEP1(v) asm volatile("" :: "v"(v))

template<int IIN>
__device__ __forceinline__ void wprefetch(const float* __restrict__ W,
                                          const float* __restrict__ bias,
                                          int c0, int lane,
                                          float4 (&wr)[2][IIN / 256],
                                          float& b0, float& b1) {
    #pragma unroll
    for (int cc = 0; cc < 2; ++cc) {
        const float4* Wr = reinterpret_cast<const float4*>(W + (size_t)(c0 + cc) * IIN);
        #pragma unroll
        for (int q = 0; q < IIN / 256; ++q) wr[cc][q] = Wr[q * 64 + lane];
    }
    b0 = bias[c0]; b1 = bias[c0 + 1];
}

// ROWS=8 rows staged in LDS; each wave computes 2 columns (w in registers).
// AIN:  stage via relaxed agent atomic u64 loads (L3-coherent, cache-bypass)
// AOUT: write via relaxed agent atomic f32 stores
template<int IIN, int OUT, int ROWS, int CPB, bool AIN, bool AOUT>
__device__ __forceinline__ void phase(const float* __restrict__ vin,   // [.., IIN] at rows0
                                      const float4 (&wr)[2][IIN / 256],
                                      float b0, float b1,
                                      float* __restrict__ vout,        // [32, OUT]
                                      float* __restrict__ lds,
                                      float* __restrict__ s1s,
                                      float* __restrict__ s2s,
                                      int rows0, int c0, int lane, int wave,
                                      float A0, float A1, float A2,
                                      float Dd, float scale)
{
    // ---- stage ROWS x IIN rows into LDS ----
    if (AIN) {
        const unsigned long long* src = reinterpret_cast<const unsigned long long*>(
            vin + (size_t)rows0 * IIN);
        float2* dst = reinterpret_cast<float2*>(lds);
        constexpr int N2 = ROWS * IIN / 2;
        #pragma unroll
        for (int k = 0; k < N2 / 256; ++k) {
            unsigned long long u = __hip_atomic_load(
                &src[k * 256 + threadIdx.x], __ATOMIC_RELAXED, __HIP_MEMORY_SCOPE_AGENT);
            float2 f;
            __builtin_memcpy(&f, &u, 8);
            dst[k * 256 + threadIdx.x] = f;
        }
    } else {
        const float4* src = reinterpret_cast<const float4*>(vin + (size_t)rows0 * IIN);
        float4* dst = reinterpret_cast<float4*>(lds);
        constexpr int N4 = ROWS * IIN / 4;
        #pragma unroll
        for (int k = 0; k < N4 / 256; ++k)
            dst[k * 256 + threadIdx.x] = src[k * 256 + threadIdx.x];
    }
    __syncthreads();

    // ---- per-row s1, s2 (ROWS/4 rows per wave) ----
    constexpr int RPW = ROWS / 4;
    #pragma unroll
    for (int r = 0; r < RPW; ++r) {
        const int b = wave * RPW + r;
        const float4* v4 = reinterpret_cast<const float4*>(lds + b * IIN);
        float p1 = 0.f, p2 = 0.f;
        #pragma unroll
        for (int q = 0; q < IIN / 256; ++q) {
            const float4 a = v4[q * 64 + lane];
            p1 += (a.x + a.y) + (a.z + a.w);
            p2 += a.x * a.x + a.y * a.y + a.z * a.z + a.w * a.w;
        }
        #pragma unroll
        for (int s = 32; s > 0; s >>= 1) {
            p1 += __shfl_xor(p1, s);
            p2 += __shfl_xor(p2, s);
        }
        if (lane == 0) { s1s[b] = p1; s2s[b] = p2; }
    }

    // ---- dots: 2 columns per wave vs ROWS staged rows ----
    float acc0[ROWS], acc1[ROWS];
    #pragma unroll
    for (int r = 0; r < ROWS; ++r) { acc0[r] = 0.f; acc1[r] = 0.f; }

    #pragma unroll
    for (int q = 0; q < IIN / 256; ++q) {
        const float4 w0 = wr[0][q];
        const float4 w1 = wr[1][q];
        #pragma unroll
        for (int r = 0; r < ROWS; ++r) {
            const float4 v4 = *reinterpret_cast<const float4*>(
                lds + r * IIN + (q * 64 + lane) * 4);
            acc0[r] = fmaf(w0.w, v4.w, fmaf(w0.z, v4.z,
                      fmaf(w0.y, v4.y, fmaf(w0.x, v4.x, acc0[r]))));
            acc1[r] = fmaf(w1.w, v4.w, fmaf(w1.z, v4.z,
                      fmaf(w1.y, v4.y, fmaf(w1.x, v4.x, acc1[r]))));
        }
    }

    // ---- paired butterfly reduce: lane pair (2r, 2r+1) keeps row r's two cols ----
    float Wv = 0.f;
    #pragma unroll
    for (int r = 0; r < ROWS; ++r) {
        const float u = acc0[r] + __shfl_xor(acc0[r], 1);
        const float w = acc1[r] + __shfl_xor(acc1[r], 1);
        float z = (lane & 1) ? w : u;
        #pragma unroll
        for (int s = 2; s < 64; s <<= 1) z += __shfl_xor(z, s);
        if ((lane >> 1) == r) Wv = z;    // even lane: col c0, odd lane: col c0+1
    }

    __syncthreads();   // s1s/s2s complete before epilogue reads

    // ---- epilogue: lane l -> (row l>>1, col c0+(l&1)) ----
    if (wave < CPB / 2 && lane < 2 * ROWS) {
        const int row = lane >> 1;
        const int col = c0 + (lane & 1);
        const float bias = (lane & 1) ? b1 : b0;
        const float vj  = fmaxf(Wv + bias, 0.f);
        const float val = vj + scale * (A0 * s2s[row] + A1 * Wv
                                        + (A2 * vj + Dd) * s1s[row]);
        float* dst = vout + (size_t)(rows0 + row) * OUT + col;
        if (AOUT)
            __hip_atomic_store(dst, val, __ATOMIC_RELAXED, __HIP_MEMORY_SCOPE_AGENT);
        else
            *dst = val;
    }
}

__global__ void __launch_bounds__(256, 1)
diffnet_onekernel(const float* __restrict__ x,
                  const float* __restrict__ W1, const float* __restrict__ b1,
                  const float* __restrict__ W2, const float* __restrict__ b2,
                  const float* __restrict__ W3, const float* __restrict__ b3,
                  const float* __restrict__ c1w, const float* __restrict__ c1b,
                  const float* __restrict__ c2w, const float* __restrict__ c2b,
                  const int* __restrict__ bn,
                  float* __restrict__ t1, float* __restrict__ t2,
                  float* __restrict__ out)
{
    __shared__ float lds[8 * 1024];       // 32 KB (phase 1: 8 rows x 1024)
    __shared__ float s1s[8], s2s[8];

    const int bid  = blockIdx.x;
    const int dom  = bid >> 6;            // 4 domains x 64 blocks
    const int j    = bid & 63;
    const int rows0 = dom * 8;
    const int lane = threadIdx.x & 63;
    const int wave = threadIdx.x >> 6;

    // epoch base (safe: flag can't advance until this block arrives at bar 1)
    unsigned int F0 = 0;
    if (threadIdx.x == 0)
        F0 = __hip_atomic_load(&g_flag[dom * 32], __ATOMIC_RELAXED,
                               __HIP_MEMORY_SCOPE_AGENT);

    // collapsed conv constants (uniform scalar loads)
    float A0 = 0.f, A1 = 0.f, A2 = 0.f, Dd = c2b[0];
    #pragma unroll
    for (int h = 0; h < 8; ++h) {
        const float w2 = c2w[h];
        A0 = fmaf(w2, c1w[h * 3 + 0], A0);
        A1 = fmaf(w2, c1w[h * 3 + 1], A1);
        A2 = fmaf(w2, c1w[h * 3 + 2], A2);
        Dd = fmaf(w2, c1b[h], Dd);
    }
    const int raw = bn[0];
    const float bnf = (raw > 0 && raw < 1000000) ? (float)raw : __int_as_float(raw);
    const float scale = 0.1f / bnf;

    const int c12 = j * 8 + wave * 2;           // phase 1/2: 8 cols/block
    const int c3  = j * 4 + (wave & 1) * 2;     // phase 3: 4 cols/block (waves 2,3 mirror)

    // ---- phase 1: x[rows,1024] -> t1[rows,512] ----
    float4 w1r[2][4];
    float b1a, b1b;
    wprefetch<1024>(W1, b1, c12, lane, w1r, b1a, b1b);
    phase<1024, 512, 8, 8, false, true>(x, w1r, b1a, b1b, t1, lds, s1s, s2s,
                                        rows0, c12, lane, wave,
                                        A0, A1, A2, Dd, scale);

    // ---- prefetch phase-2 weights BEFORE the barrier ----
    float4 w2r[2][2];
    float b2a, b2b;
    wprefetch<512>(W2, b2, c12, lane, w2r, b2a, b2b);
    KEEP4(w2r[0][0]); KEEP4(w2r[0][1]); KEEP4(w2r[1][0]); KEEP4(w2r[1][1]);
    KEEP1(b2a); KEEP1(b2b);

    gridbar(dom, F0 + 1);

    // ---- phase 2: t1[rows,512] -> t2[rows,512] ----
    phase<512, 512, 8, 8, true, true>(t1, w2r, b2a, b2b, t2, lds, s1s, s2s,
                                      rows0, c12, lane, wave,
                                      A0, A1, A2, Dd, scale);

    // ---- prefetch phase-3 weights BEFORE the barrier ----
    float4 w3r[2][2];
    float b3a, b3b;
    wprefetch<512>(W3, b3, c3, lane, w3r, b3a, b3b);
    KEEP4(w3r[0][0]); KEEP4(w3r[0][1]); KEEP4(w3r[1][0]); KEEP4(w3r[1][1]);
    KEEP1(b3a); KEEP1(b3b);

    gridbar(dom, F0 + 2);

    // ---- phase 3: t2[rows,512] -> out[rows,256] (plain stores) ----
    phase<512, 256, 8, 4, true, false>(t2, w3r, b3a, b3b, out, lds, s1s, s2s,
                                       rows0, c3, lane, wave,
                                       A0, A1, A2, Dd, scale);
}

extern "C" void kernel_launch(void* const* d_in, const int* in_sizes, int n_in,
                              void* d_out, int out_size, void* d_ws, size_t ws_size,
                              hipStream_t stream) {
    const float* x     = (const float*)d_in[0];
    const float* fc1_w = (const float*)d_in[1];
    const float* fc1_b = (const float*)d_in[2];
    const float* fc2_w = (const float*)d_in[3];
    const float* fc2_b = (const float*)d_in[4];
    const float* fc3_w = (const float*)d_in[5];
    const float* fc3_b = (const float*)d_in[6];
    const float* c1w   = (const float*)d_in[7];
    const float* c1b   = (const float*)d_in[8];
    const float* c2w   = (const float*)d_in[9];
    const float* c2b   = (const float*)d_in[10];
    const int*   bn    = (const int*)d_in[11];

    float* t1  = (float*)d_ws;                         // [32, 512] = 64KB
    float* t2  = t1 + 32 * 512;                        // [32, 512] = 64KB
    float* out = (float*)d_out;                        // [32, 256]

    diffnet_onekernel<<<dim3(NBLK), dim3(256), 0, stream>>>(
        x, fc1_w, fc1_b, fc2_w, fc2_b, fc3_w, fc3_b,
        c1w, c1b, c2w, c2b, bn, t1, t2, out);
}